// Round 9
// baseline (8860.320 us; speedup 1.0000x reference)
//
#include <hip/hip_runtime.h>

#define T_STEPS 32768
#define DIN 256
#define HID 64
#define G3 192
#define JJ 1024
#define PF 4          // gi register-prefetch depth (steps ahead)

typedef float f4 __attribute__((ext_vector_type(4)));

__device__ __forceinline__ float hsum4(f4 v) { return (v.x + v.y) + (v.z + v.w); }

// quad reduction via DPP: sum of the 4 lanes in each DPP quad, result in all 4.
// quad_perm[1,0,3,2]=0xB1 (xor-1), quad_perm[2,3,0,1]=0x4E (xor-2). Pure VALU,
// no DS pipe. Association (c0+c1)+(c2+c3) == hsum4 of column partials.
__device__ __forceinline__ float qsum(float v) {
    float a = __int_as_float(__builtin_amdgcn_mov_dpp(__float_as_int(v), 0xB1, 0xF, 0xF, true));
    float s = v + a;
    float b = __int_as_float(__builtin_amdgcn_mov_dpp(__float_as_int(s), 0x4E, 0xF, 0xF, true));
    return s + b;
}

// ---------------- K1: gi = x @ w_ih^T + b_ih  (T x 192) ----------------
// R8: was LDS-issue-bound (per k4, per thread: 32 ds_read_b128 for 32 f4-FMA,
// DS:FMA = 1:1 -> ~2048 DS instr/wave ~ 123us). New layout: thread (rg,cg)
// owns 4 rows x 8 cols -> per k4: 4 DS reads feed 32 f4-FMAs (1:8).
// Per-output accumulation order unchanged -> bit-identical gi.
__global__ __launch_bounds__(192)
void k_gi(const float* __restrict__ states, const float* __restrict__ w_ih,
          const float* __restrict__ b_ih, float* __restrict__ gi)
{
    __shared__ __align__(16) float xs[32 * DIN];   // 32 KB x-tile
    const int tid  = threadIdx.x;
    const int row0 = blockIdx.x * 32;

    for (int i = tid; i < 32 * DIN; i += 192)
        xs[i] = states[(size_t)(row0 + (i >> 8)) * (DIN + 3) + (i & 255)];
    __syncthreads();

    const int cg = tid % 24;          // col group: cols cg + 24q, q=0..7
    const int rg = tid / 24;          // row group: rows rg*4 .. rg*4+3

    float acc[4][8];
#pragma unroll
    for (int rr = 0; rr < 4; ++rr)
#pragma unroll
        for (int q = 0; q < 8; ++q) acc[rr][q] = 0.f;

    for (int k4 = 0; k4 < DIN / 4; ++k4) {
        float4 wv[8];
#pragma unroll
        for (int q = 0; q < 8; ++q)
            wv[q] = *(const float4*)&w_ih[(size_t)(cg + 24 * q) * DIN + k4 * 4];
        float4 xv[4];
#pragma unroll
        for (int rr = 0; rr < 4; ++rr)
            xv[rr] = *(const float4*)&xs[(rg * 4 + rr) * DIN + k4 * 4];  // LDS broadcast
#pragma unroll
        for (int rr = 0; rr < 4; ++rr)
#pragma unroll
            for (int q = 0; q < 8; ++q)
                acc[rr][q] += xv[rr].x * wv[q].x + xv[rr].y * wv[q].y +
                              xv[rr].z * wv[q].z + xv[rr].w * wv[q].w;
    }

#pragma unroll
    for (int q = 0; q < 8; ++q) {
        const int c = cg + 24 * q;
        const float bi = b_ih[c];
#pragma unroll
        for (int rr = 0; rr < 4; ++rr)
            gi[(size_t)(row0 + rg * 4 + rr) * G3 + c] = acc[rr][q] + bi;
    }
}

// ---------------- K2: sequential GRU scan, DPP-quad K-split -----------------
// BYTE-IDENTICAL to R7 (proven 8358 us): 256 threads = 4 waves (1/SIMD).
// Lane l of wave w: element e=16w+(l>>2), K-chunk c=l&3 (16 wide). 4
// K-partials live in one DPP quad -> 2 DPP adds replace the LDS partial
// exchange. Only h crosses waves: 16 predicated ds_writes/wave, one raw
// barrier (lgkmcnt-only wait; vmcnt / gi prefetch stays in flight), 4
// broadcast ds_read_b128. h double-buffered by parity. Gate-chain folds:
// pre-folded exp2 args, z-chain computes (1-z) and z*h in parallel with the
// n-chain -> single fma after n.
__global__ __launch_bounds__(256)
void k_scan(const float* __restrict__ gi, const float* __restrict__ w_hh,
            const float* __restrict__ b_hh, const float* __restrict__ h0,
            float* __restrict__ hs, float* __restrict__ h_final)
{
    __shared__ __align__(16) float hsh[2][HID];   // double-buffered h (512 B)

    const int tid = threadIdx.x;
    const int w   = tid >> 6;            // wave id 0..3
    const int l   = tid & 63;            // lane id
    const int e   = w * 16 + (l >> 2);   // element this lane computes
    const int c   = l & 3;               // K-chunk (16 wide)
    const bool own = (c == 0);           // 16 lanes/wave own the writes

    // weights: rows e / e+64 / e+128, cols [16c,16c+16) -> 12 named f4
    f4 wr0, wr1, wr2, wr3, wz0, wz1, wz2, wz3, wn0, wn1, wn2, wn3;
    {
        const float* r0 = w_hh + (size_t)e         * HID + c * 16;
        const float* r1 = w_hh + (size_t)(e + 64)  * HID + c * 16;
        const float* r2 = w_hh + (size_t)(e + 128) * HID + c * 16;
        wr0 = *(const f4*)&r0[0];  wr1 = *(const f4*)&r0[4];
        wr2 = *(const f4*)&r0[8];  wr3 = *(const f4*)&r0[12];
        wz0 = *(const f4*)&r1[0];  wz1 = *(const f4*)&r1[4];
        wz2 = *(const f4*)&r1[8];  wz3 = *(const f4*)&r1[12];
        wn0 = *(const f4*)&r2[0];  wn1 = *(const f4*)&r2[4];
        wn2 = *(const f4*)&r2[8];  wn3 = *(const f4*)&r2[12];
    }
    const float bhr = b_hh[e];
    const float bhz = b_hh[e + 64];
    const float bhn = b_hh[e + 128];

    const float LOG2E  =  1.44269504088896340736f;
    const float NLOG2E = -1.44269504088896340736f;
    const float L2E2   =  2.88539008177792681472f;   // 2*log2(e)
    const float crb  = NLOG2E * bhr;     // sigmoid bias pre-folded into exp2 arg
    const float czb  = NLOG2E * bhz;
    const float bhn2 = L2E2 * bhn;       // n-gate bias pre-folded into exp2 arg

    float hv = h0[e];                    // this lane's element (4x replicated/quad)
    if (own) hsh[0][e] = hv;             // fill step-0 read buffer
    __syncthreads();                     // one-time pre-loop sync

    // rotating gi prefetch, PF steps ahead (uniform row offset -> SALU/saddr)
    float pr[PF], pz[PF], pn[PF];
#pragma unroll
    for (int j = 0; j < PF; ++j) {
        pr[j] = gi[(size_t)j * G3 + e];
        pz[j] = gi[(size_t)j * G3 + e + 64];
        pn[j] = gi[(size_t)j * G3 + e + 128];
    }

#pragma unroll PF
    for (int s = 0; s < T_STEPS; ++s) {
        const int j = s & (PF - 1);      // compile-time per unrolled copy

        // ---- h quads FIRST (critical chain: issue the DS reads asap) ----
        const float* hb = &hsh[s & 1][c * 16];
        const f4 hq0 = *(const f4*)&hb[0];
        const f4 hq1 = *(const f4*)&hb[4];
        const f4 hq2 = *(const f4*)&hb[8];
        const f4 hq3 = *(const f4*)&hb[12];

        const float gir = pr[j], giz = pz[j], gin = pn[j];

        // ---- gi reloads issued into the DS read-latency shadow ----
        const int sp = (s + PF) & (T_STEPS - 1);   // wraps: address stays valid
        pr[j] = gi[(size_t)sp * G3 + e];
        pz[j] = gi[(size_t)sp * G3 + e + 64];
        pn[j] = gi[(size_t)sp * G3 + e + 128];

        // ---- local matvec over the 16-wide chunk (quad-major interleave);
        //      first op = mul (fma(w,h,0) == w*h bitwise) ----
        f4 ar4 = wr0 * hq0;
        f4 az4 = wz0 * hq0;
        f4 an4 = wn0 * hq0;
        ar4 = __builtin_elementwise_fma(wr1, hq1, ar4);
        az4 = __builtin_elementwise_fma(wz1, hq1, az4);
        an4 = __builtin_elementwise_fma(wn1, hq1, an4);
        ar4 = __builtin_elementwise_fma(wr2, hq2, ar4);
        az4 = __builtin_elementwise_fma(wz2, hq2, az4);
        an4 = __builtin_elementwise_fma(wn2, hq2, an4);
        ar4 = __builtin_elementwise_fma(wr3, hq3, ar4);
        az4 = __builtin_elementwise_fma(wz3, hq3, az4);
        an4 = __builtin_elementwise_fma(wn3, hq3, an4);

        // ---- intra-quad 4-way reduction (DPP, no LDS, no barrier) ----
        const float ar = qsum(hsum4(ar4));
        const float az = qsum(hsum4(az4));
        const float qn = qsum(hsum4(an4));

        // off-chain / parallel-chain pre-products
        const float cr   = __builtin_fmaf(NLOG2E, gir, crb);
        const float cz   = __builtin_fmaf(NLOG2E, giz, czb);
        const float gin2 = L2E2 * gin;                      // off-chain
        const float an2  = __builtin_fmaf(qn, L2E2, bhn2);  // fma replaces add

        // r-sigmoid (chain: fma, exp, add, rcp)
        const float er = __builtin_amdgcn_exp2f(__builtin_fmaf(ar, NLOG2E, cr));
        const float r  = __builtin_amdgcn_rcpf(1.f + er);

        // z-sigmoid (parallel chain; finishes before n-chain)
        const float ez = __builtin_amdgcn_exp2f(__builtin_fmaf(az, NLOG2E, cz));
        const float z  = __builtin_amdgcn_rcpf(1.f + ez);
        const float zc  = 1.f - z;        // on z-chain, parallel to n-chain
        const float zhv = z * hv;         // on z-chain, parallel to n-chain

        // n-tanh: u = e^(2*npre) via pre-folded products (one mul removed)
        const float u  = __builtin_amdgcn_exp2f(__builtin_fmaf(r, an2, gin2));
        const float wn = __builtin_amdgcn_rcpf(u + 1.f);
        const float n  = __builtin_fmaf(-2.f, wn, 1.f);

        hv = __builtin_fmaf(zc, n, zhv);  // single fma after n

        // ---- publish h for next step (opposite parity buffer) + hs store ----
        if (own) {
            hsh[(s + 1) & 1][e] = hv;             // 16 consecutive floats/wave
            hs[(size_t)s * HID + e] = hv;         // uniform row offset -> saddr
        }

        // raw barrier: wait LDS writes only; vmcnt (gi prefetch + hs store)
        // stays in flight
        asm volatile("s_waitcnt lgkmcnt(0)\n\ts_barrier" ::: "memory");
    }
    if (own) h_final[e] = hv;
}

// ---------------- K3: logits = hs @ w_out^T + b_out, masked ----------------
// R8: halve DS instruction count (was 16 ds_read_b128 per 64 f4-FMA per k4;
// now thread (rg,cg) owns 8 rows x 8 cols -> 8 DS reads per 64 f4-FMA).
// Same k4-major dot association -> bit-identical logits. Stores stay
// lane-consecutive (c = cg + 128q, cg = tid&127) -> coalesced.
__global__ __launch_bounds__(256)
void k_out(const float* __restrict__ hs, const float* __restrict__ w_out,
           const float* __restrict__ b_out, const int* __restrict__ mask,
           float* __restrict__ out)
{
    __shared__ __align__(16) float hs_s[16 * HID];
    const int tid  = threadIdx.x;
    const int row0 = blockIdx.x * 16;

    {   // stage 16 rows of hs (contiguous 1024 floats)
        const float4 v = *(const float4*)&hs[(size_t)row0 * HID + tid * 4];
        *(float4*)&hs_s[tid * 4] = v;
    }
    __syncthreads();

    const int cg = tid & 127;         // col group: cols cg + 128q, q=0..7
    const int rg = tid >> 7;          // row group: rows rg*8 .. rg*8+7

    float acc[8][8];
#pragma unroll
    for (int rr = 0; rr < 8; ++rr)
#pragma unroll
        for (int q = 0; q < 8; ++q) acc[rr][q] = 0.f;

    for (int k4 = 0; k4 < HID / 4; ++k4) {
        float4 wv[8];
#pragma unroll
        for (int q = 0; q < 8; ++q)
            wv[q] = *(const float4*)&w_out[(size_t)(cg + 128 * q) * HID + k4 * 4];
        float4 hv[8];
#pragma unroll
        for (int rr = 0; rr < 8; ++rr)
            hv[rr] = *(const float4*)&hs_s[(rg * 8 + rr) * HID + k4 * 4];  // broadcast
#pragma unroll
        for (int rr = 0; rr < 8; ++rr)
#pragma unroll
            for (int q = 0; q < 8; ++q)
                acc[rr][q] += hv[rr].x * wv[q].x + hv[rr].y * wv[q].y +
                              hv[rr].z * wv[q].z + hv[rr].w * wv[q].w;
    }

#pragma unroll
    for (int q = 0; q < 8; ++q) {
        const int c = cg + 128 * q;
        const float bo = b_out[c];
        const int m = mask[c];
#pragma unroll
        for (int rr = 0; rr < 8; ++rr) {
            const float v = (m == 0) ? -1e9f : (acc[rr][q] + bo);
            out[(size_t)(row0 + rg * 8 + rr) * JJ + c] = v;
        }
    }
}

// ---------------- launch ----------------
extern "C" void kernel_launch(void* const* d_in, const int* in_sizes, int n_in,
                              void* d_out, int out_size, void* d_ws, size_t ws_size,
                              hipStream_t stream)
{
    const float* states = (const float*)d_in[0];
    const float* h0     = (const float*)d_in[1];
    const float* w_ih   = (const float*)d_in[2];
    const float* w_hh   = (const float*)d_in[3];
    const float* b_ih   = (const float*)d_in[4];
    const float* b_hh   = (const float*)d_in[5];
    const float* w_out  = (const float*)d_in[6];
    const float* b_out  = (const float*)d_in[7];
    const int*   mask   = (const int*)d_in[8];

    float* out = (float*)d_out;
    float* gi  = (float*)d_ws;                         // T*192 fp32 = 25.2 MB
    float* hs  = gi + (size_t)T_STEPS * G3;            // T*64  fp32 =  8.4 MB
    float* h_final = out + (size_t)T_STEPS * JJ;       // after logits

    k_gi  <<<dim3(T_STEPS / 32), dim3(192), 0, stream>>>(states, w_ih, b_ih, gi);
    k_scan<<<dim3(1),            dim3(256), 0, stream>>>(gi, w_hh, b_hh, h0, hs, h_final);
    k_out <<<dim3(T_STEPS / 16), dim3(256), 0, stream>>>(hs, w_out, b_out, mask, out);
}

// Round 10
// 8725.672 us; speedup vs baseline: 1.0154x; 1.0154x over previous
//
#include <hip/hip_runtime.h>

#define T_STEPS 32768
#define DIN 256
#define HID 64
#define G3 192
#define JJ 1024
#define PF 4          // gi register-prefetch depth (steps ahead)

typedef float f4 __attribute__((ext_vector_type(4)));

__device__ __forceinline__ float hsum4(f4 v) { return (v.x + v.y) + (v.z + v.w); }

// quad reduction via DPP: sum of the 4 lanes in each DPP quad, result in all 4.
// quad_perm[1,0,3,2]=0xB1 (xor-1), quad_perm[2,3,0,1]=0x4E (xor-2). Pure VALU,
// no DS pipe. Association (c0+c1)+(c2+c3) == hsum4 of column partials.
__device__ __forceinline__ float qsum(float v) {
    float a = __int_as_float(__builtin_amdgcn_mov_dpp(__float_as_int(v), 0xB1, 0xF, 0xF, true));
    float s = v + a;
    float b = __int_as_float(__builtin_amdgcn_mov_dpp(__float_as_int(s), 0x4E, 0xF, 0xF, true));
    return s + b;
}

// ---------------- K1: gi = x @ w_ih^T + b_ih  (T x 192) ----------------
// R9: R0's version was DS-issue-bound (1:1 DS:FMA, 2048 b128/wave ~ 123us);
// R8's fix broke VMEM (8x-duplicated uncoalesced global W loads). This one
// fixes both: W staged in LDS per 16-wide K-chunk (coalesced, once per
// block), X tile padded to stride 268 (2-way bank aliasing = free), thread =
// 4 rows x 8 cols -> 12 DS reads per 32 FMA4. k-sequential accumulation per
// output -> bit-identical gi.
#define XS_STR 268   // 32 rows; 268 % 32 = 12, gcd 4 -> rows 0..11 max 2-way
#define WS_STR 20    // 192 rows x 16 K; 80 B rows (16B-aligned), <=3-way

__global__ __launch_bounds__(192)
void k_gi(const float* __restrict__ states, const float* __restrict__ w_ih,
          const float* __restrict__ b_ih, float* __restrict__ gi)
{
    __shared__ __align__(16) float xs[32 * XS_STR];   // 34.3 KB
    __shared__ __align__(16) float ws[192 * WS_STR];  // 15.4 KB
    const int tid  = threadIdx.x;
    const int row0 = blockIdx.x * 32;

    for (int i = tid; i < 32 * DIN; i += 192)
        xs[(i >> 8) * XS_STR + (i & 255)] =
            states[(size_t)(row0 + (i >> 8)) * (DIN + 3) + (i & 255)];

    const int cg = tid % 24;          // col group: cols cg + 24q, q=0..7
    const int rg = tid / 24;          // row group: rows rg*4 .. rg*4+3

    float acc[4][8];
#pragma unroll
    for (int rr = 0; rr < 4; ++rr)
#pragma unroll
        for (int q = 0; q < 8; ++q) acc[rr][q] = 0.f;

    for (int kc = 0; kc < DIN / 16; ++kc) {
        __syncthreads();   // ws free of prev chunk's readers (kc=0: xs ready)
        // stage W chunk [192 rows x 16 K] cooperatively, coalesced
#pragma unroll
        for (int i2 = 0; i2 < 4; ++i2) {
            const int v  = tid + 192 * i2;       // 0..767 float4s
            const int c  = v >> 2;
            const int kq = v & 3;
            *(float4*)&ws[c * WS_STR + kq * 4] =
                *(const float4*)&w_ih[(size_t)c * DIN + kc * 16 + kq * 4];
        }
        __syncthreads();

#pragma unroll
        for (int k4 = 0; k4 < 4; ++k4) {
            const int kb = kc * 16 + k4 * 4;
            float4 xv[4];
#pragma unroll
            for (int rr = 0; rr < 4; ++rr)
                xv[rr] = *(const float4*)&xs[(rg * 4 + rr) * XS_STR + kb];
            float4 wv[8];
#pragma unroll
            for (int q = 0; q < 8; ++q)
                wv[q] = *(const float4*)&ws[(cg + 24 * q) * WS_STR + k4 * 4];
#pragma unroll
            for (int rr = 0; rr < 4; ++rr)
#pragma unroll
                for (int q = 0; q < 8; ++q)
                    acc[rr][q] += xv[rr].x * wv[q].x + xv[rr].y * wv[q].y +
                                  xv[rr].z * wv[q].z + xv[rr].w * wv[q].w;
        }
    }

#pragma unroll
    for (int q = 0; q < 8; ++q) {
        const int c = cg + 24 * q;
        const float bi = b_ih[c];
#pragma unroll
        for (int rr = 0; rr < 4; ++rr)
            gi[(size_t)(row0 + rg * 4 + rr) * G3 + c] = acc[rr][q] + bi;
    }
}

// ---------------- K2: sequential GRU scan, DPP-quad K-split -----------------
// BYTE-IDENTICAL to R7/R8 (proven 8324-8358 us): 256 threads = 4 waves
// (1/SIMD). Lane l of wave w: element e=16w+(l>>2), K-chunk c=l&3 (16 wide).
// 4 K-partials live in one DPP quad -> 2 DPP adds replace the LDS partial
// exchange. Only h crosses waves: 16 predicated ds_writes/wave, one raw
// barrier (lgkmcnt-only wait; vmcnt / gi prefetch stays in flight), 4
// broadcast ds_read_b128. h double-buffered by parity. Gate-chain folds:
// pre-folded exp2 args, z-chain computes (1-z) and z*h in parallel with the
// n-chain -> single fma after n.
__global__ __launch_bounds__(256)
void k_scan(const float* __restrict__ gi, const float* __restrict__ w_hh,
            const float* __restrict__ b_hh, const float* __restrict__ h0,
            float* __restrict__ hs, float* __restrict__ h_final)
{
    __shared__ __align__(16) float hsh[2][HID];   // double-buffered h (512 B)

    const int tid = threadIdx.x;
    const int w   = tid >> 6;            // wave id 0..3
    const int l   = tid & 63;            // lane id
    const int e   = w * 16 + (l >> 2);   // element this lane computes
    const int c   = l & 3;               // K-chunk (16 wide)
    const bool own = (c == 0);           // 16 lanes/wave own the writes

    // weights: rows e / e+64 / e+128, cols [16c,16c+16) -> 12 named f4
    f4 wr0, wr1, wr2, wr3, wz0, wz1, wz2, wz3, wn0, wn1, wn2, wn3;
    {
        const float* r0 = w_hh + (size_t)e         * HID + c * 16;
        const float* r1 = w_hh + (size_t)(e + 64)  * HID + c * 16;
        const float* r2 = w_hh + (size_t)(e + 128) * HID + c * 16;
        wr0 = *(const f4*)&r0[0];  wr1 = *(const f4*)&r0[4];
        wr2 = *(const f4*)&r0[8];  wr3 = *(const f4*)&r0[12];
        wz0 = *(const f4*)&r1[0];  wz1 = *(const f4*)&r1[4];
        wz2 = *(const f4*)&r1[8];  wz3 = *(const f4*)&r1[12];
        wn0 = *(const f4*)&r2[0];  wn1 = *(const f4*)&r2[4];
        wn2 = *(const f4*)&r2[8];  wn3 = *(const f4*)&r2[12];
    }
    const float bhr = b_hh[e];
    const float bhz = b_hh[e + 64];
    const float bhn = b_hh[e + 128];

    const float LOG2E  =  1.44269504088896340736f;
    const float NLOG2E = -1.44269504088896340736f;
    const float L2E2   =  2.88539008177792681472f;   // 2*log2(e)
    const float crb  = NLOG2E * bhr;     // sigmoid bias pre-folded into exp2 arg
    const float czb  = NLOG2E * bhz;
    const float bhn2 = L2E2 * bhn;       // n-gate bias pre-folded into exp2 arg

    float hv = h0[e];                    // this lane's element (4x replicated/quad)
    if (own) hsh[0][e] = hv;             // fill step-0 read buffer
    __syncthreads();                     // one-time pre-loop sync

    // rotating gi prefetch, PF steps ahead (uniform row offset -> SALU/saddr)
    float pr[PF], pz[PF], pn[PF];
#pragma unroll
    for (int j = 0; j < PF; ++j) {
        pr[j] = gi[(size_t)j * G3 + e];
        pz[j] = gi[(size_t)j * G3 + e + 64];
        pn[j] = gi[(size_t)j * G3 + e + 128];
    }

#pragma unroll PF
    for (int s = 0; s < T_STEPS; ++s) {
        const int j = s & (PF - 1);      // compile-time per unrolled copy

        // ---- h quads FIRST (critical chain: issue the DS reads asap) ----
        const float* hb = &hsh[s & 1][c * 16];
        const f4 hq0 = *(const f4*)&hb[0];
        const f4 hq1 = *(const f4*)&hb[4];
        const f4 hq2 = *(const f4*)&hb[8];
        const f4 hq3 = *(const f4*)&hb[12];

        const float gir = pr[j], giz = pz[j], gin = pn[j];

        // ---- gi reloads issued into the DS read-latency shadow ----
        const int sp = (s + PF) & (T_STEPS - 1);   // wraps: address stays valid
        pr[j] = gi[(size_t)sp * G3 + e];
        pz[j] = gi[(size_t)sp * G3 + e + 64];
        pn[j] = gi[(size_t)sp * G3 + e + 128];

        // ---- local matvec over the 16-wide chunk (quad-major interleave);
        //      first op = mul (fma(w,h,0) == w*h bitwise) ----
        f4 ar4 = wr0 * hq0;
        f4 az4 = wz0 * hq0;
        f4 an4 = wn0 * hq0;
        ar4 = __builtin_elementwise_fma(wr1, hq1, ar4);
        az4 = __builtin_elementwise_fma(wz1, hq1, az4);
        an4 = __builtin_elementwise_fma(wn1, hq1, an4);
        ar4 = __builtin_elementwise_fma(wr2, hq2, ar4);
        az4 = __builtin_elementwise_fma(wz2, hq2, az4);
        an4 = __builtin_elementwise_fma(wn2, hq2, an4);
        ar4 = __builtin_elementwise_fma(wr3, hq3, ar4);
        az4 = __builtin_elementwise_fma(wz3, hq3, az4);
        an4 = __builtin_elementwise_fma(wn3, hq3, an4);

        // ---- intra-quad 4-way reduction (DPP, no LDS, no barrier) ----
        const float ar = qsum(hsum4(ar4));
        const float az = qsum(hsum4(az4));
        const float qn = qsum(hsum4(an4));

        // off-chain / parallel-chain pre-products
        const float cr   = __builtin_fmaf(NLOG2E, gir, crb);
        const float cz   = __builtin_fmaf(NLOG2E, giz, czb);
        const float gin2 = L2E2 * gin;                      // off-chain
        const float an2  = __builtin_fmaf(qn, L2E2, bhn2);  // fma replaces add

        // r-sigmoid (chain: fma, exp, add, rcp)
        const float er = __builtin_amdgcn_exp2f(__builtin_fmaf(ar, NLOG2E, cr));
        const float r  = __builtin_amdgcn_rcpf(1.f + er);

        // z-sigmoid (parallel chain; finishes before n-chain)
        const float ez = __builtin_amdgcn_exp2f(__builtin_fmaf(az, NLOG2E, cz));
        const float z  = __builtin_amdgcn_rcpf(1.f + ez);
        const float zc  = 1.f - z;        // on z-chain, parallel to n-chain
        const float zhv = z * hv;         // on z-chain, parallel to n-chain

        // n-tanh: u = e^(2*npre) via pre-folded products (one mul removed)
        const float u  = __builtin_amdgcn_exp2f(__builtin_fmaf(r, an2, gin2));
        const float wn = __builtin_amdgcn_rcpf(u + 1.f);
        const float n  = __builtin_fmaf(-2.f, wn, 1.f);

        hv = __builtin_fmaf(zc, n, zhv);  // single fma after n

        // ---- publish h for next step (opposite parity buffer) + hs store ----
        if (own) {
            hsh[(s + 1) & 1][e] = hv;             // 16 consecutive floats/wave
            hs[(size_t)s * HID + e] = hv;         // uniform row offset -> saddr
        }

        // raw barrier: wait LDS writes only; vmcnt (gi prefetch + hs store)
        // stays in flight
        asm volatile("s_waitcnt lgkmcnt(0)\n\ts_barrier" ::: "memory");
    }
    if (own) h_final[e] = hv;
}

// ---------------- K3: logits = hs @ w_out^T + b_out, masked ----------------
// Reverted to the proven R7 version (R8's col-blocking duplicated uncoalesced
// global W loads and regressed). DS:FMA 1:4, W read once per thread-row,
// coalesced stores.
__global__ __launch_bounds__(256)
void k_out(const float* __restrict__ hs, const float* __restrict__ w_out,
           const float* __restrict__ b_out, const int* __restrict__ mask,
           float* __restrict__ out)
{
    __shared__ __align__(16) float hs_s[16 * HID];
    const int tid  = threadIdx.x;
    const int row0 = blockIdx.x * 16;

    {   // stage 16 rows of hs (contiguous 1024 floats)
        const float4 v = *(const float4*)&hs[(size_t)row0 * HID + tid * 4];
        *(float4*)&hs_s[tid * 4] = v;
    }
    __syncthreads();

    float acc[16][4];
#pragma unroll
    for (int r = 0; r < 16; ++r)
#pragma unroll
        for (int cc = 0; cc < 4; ++cc) acc[r][cc] = 0.f;

    for (int k4 = 0; k4 < HID / 4; ++k4) {
        float4 wv[4];
#pragma unroll
        for (int cc = 0; cc < 4; ++cc)
            wv[cc] = *(const float4*)&w_out[(size_t)(cc * 256 + tid) * HID + k4 * 4];
#pragma unroll
        for (int r = 0; r < 16; ++r) {
            const float4 hv = *(const float4*)&hs_s[r * HID + k4 * 4];  // broadcast
#pragma unroll
            for (int cc = 0; cc < 4; ++cc)
                acc[r][cc] += hv.x * wv[cc].x + hv.y * wv[cc].y +
                              hv.z * wv[cc].z + hv.w * wv[cc].w;
        }
    }

#pragma unroll
    for (int cc = 0; cc < 4; ++cc) {
        const int c = cc * 256 + tid;
        const float bo = b_out[c];
        const int m = mask[c];
#pragma unroll
        for (int r = 0; r < 16; ++r) {
            const float v = (m == 0) ? -1e9f : (acc[r][cc] + bo);
            out[(size_t)(row0 + r) * JJ + c] = v;
        }
    }
}

// ---------------- launch ----------------
extern "C" void kernel_launch(void* const* d_in, const int* in_sizes, int n_in,
                              void* d_out, int out_size, void* d_ws, size_t ws_size,
                              hipStream_t stream)
{
    const float* states = (const float*)d_in[0];
    const float* h0     = (const float*)d_in[1];
    const float* w_ih   = (const float*)d_in[2];
    const float* w_hh   = (const float*)d_in[3];
    const float* b_ih   = (const float*)d_in[4];
    const float* b_hh   = (const float*)d_in[5];
    const float* w_out  = (const float*)d_in[6];
    const float* b_out  = (const float*)d_in[7];
    const int*   mask   = (const int*)d_in[8];

    float* out = (float*)d_out;
    float* gi  = (float*)d_ws;                         // T*192 fp32 = 25.2 MB
    float* hs  = gi + (size_t)T_STEPS * G3;            // T*64  fp32 =  8.4 MB
    float* h_final = out + (size_t)T_STEPS * JJ;       // after logits

    k_gi  <<<dim3(T_STEPS / 32), dim3(192), 0, stream>>>(states, w_ih, b_ih, gi);
    k_scan<<<dim3(1),            dim3(256), 0, stream>>>(gi, w_hh, b_hh, h0, hs, h_final);
    k_out <<<dim3(T_STEPS / 16), dim3(256), 0, stream>>>(hs, w_out, b_out, mask, out);
}